// Round 4
// baseline (63.596 us; speedup 1.0000x reference)
//
#include <hip/hip_runtime.h>
#include <hip/hip_bf16.h>

#define BB     8
#define NEW_S  2048
#define RES_S  4096
#define HDIM   1024          // floats per row
#define H4     (HDIM / 4)    // 256 float4 per row

#define TPB    256
#define NBLK   2048          // 8 blocks/CU * 256 CUs
#define NROWS  (BB * RES_S)               // 32768 rows
#define ITERS  (NROWS / NBLK)             // 16 rows per block
#define GRP    8                          // rows per load batch

typedef float f4 __attribute__((ext_vector_type(4)));

// ---------------------------------------------------------------------------
// Kernel A: per-batch scan of counts -> inverse map inv[b*RES_S + j] = token i
// ---------------------------------------------------------------------------
__global__ __launch_bounds__(1024) void build_inv_kernel(
    const int* __restrict__ counts, int* __restrict__ inv) {
    const int b = blockIdx.x;
    const int t = threadIdx.x;          // 0..1023
    int* invb = inv + b * RES_S;

#pragma unroll
    for (int k = 0; k < RES_S / 1024; ++k) invb[t + k * 1024] = -1;
    __syncthreads();

    const int* cb = counts + b * NEW_S;
    const int c0 = cb[2 * t];
    const int c1 = cb[2 * t + 1];

    const unsigned long long e0 =
        (unsigned long long)(unsigned)(c0 > 0 ? c0 : 0) |
        ((unsigned long long)(c0 <= 0) << 32);
    const unsigned long long e1 =
        (unsigned long long)(unsigned)(c1 > 0 ? c1 : 0) |
        ((unsigned long long)(c1 <= 0) << 32);
    const unsigned long long p = e0 + e1;

    const int lane = t & 63;
    const int wave = t >> 6;            // 0..15
    unsigned long long x = p;
#pragma unroll
    for (int d = 1; d < 64; d <<= 1) {
        unsigned long long y = __shfl_up(x, d, 64);
        if (lane >= d) x += y;
    }

    __shared__ unsigned long long wsum[16];
    if (lane == 63) wsum[wave] = x;
    __syncthreads();
    if (t == 0) {
        unsigned long long acc = 0;
#pragma unroll
        for (int w = 0; w < 16; ++w) {
            unsigned long long v = wsum[w];
            wsum[w] = acc;
            acc += v;
        }
    }
    __syncthreads();

    const unsigned long long excl  = wsum[wave] + (x - p);
    const unsigned long long incl0 = excl + e0;
    const unsigned long long incl1 = incl0 + e1;

    if ((incl0 >> 32) == 0ULL) {
        const int idx = (int)(incl0 & 0xffffffffULL) - 1;
        if (idx >= 0 && idx < RES_S) invb[idx] = 2 * t;
    }
    if ((incl1 >> 32) == 0ULL) {
        const int idx = (int)(incl1 & 0xffffffffULL) - 1;
        if (idx >= 0 && idx < RES_S) invb[idx] = 2 * t + 1;
    }
}

// ---------------------------------------------------------------------------
// Kernel B: out[b,j,:] = residual[b,j,:] + (inv[b,j] >= 0 ? hidden[b,inv,:] : 0)
// Straight-line hot path: per 8-row group, issue all 16 independent f4 loads
// (hidden address clamped to row 0 when unmapped -> L2-hit broadcast), then
// combine via per-lane select + NT store. No branches => loads batch up and
// ~16 are in flight per wave (latency hiding via MLP, not just TLP).
// ---------------------------------------------------------------------------
__global__ __launch_bounds__(256) void fanout_add_kernel(
    const f4* __restrict__ hidden,
    const f4* __restrict__ residual,
    const int* __restrict__ inv,
    f4* __restrict__ out) {
    const int t   = threadIdx.x;        // 0..255
    const int blk = blockIdx.x;         // 0..2047

    // prologue: block-uniform src indices -> SGPRs
    int src[ITERS];
#pragma unroll
    for (int k = 0; k < ITERS; ++k)
        src[k] = __builtin_amdgcn_readfirstlane(inv[blk + k * NBLK]);

#pragma unroll
    for (int g = 0; g < ITERS / GRP; ++g) {
        f4 r[GRP], h[GRP];
        // phase A: issue all loads, no consumption
#pragma unroll
        for (int j = 0; j < GRP; ++j) {
            const int k   = g * GRP + j;
            const int row = blk + k * NBLK;            // block-uniform
            r[j] = residual[(size_t)row * H4 + t];
            const int b = row >> 12;                   // row / RES_S
            const int s = src[k] >= 0 ? src[k] : 0;    // clamp: L2-hit broadcast
            h[j] = hidden[((size_t)(b << 11) + s) * H4 + t];
        }
        // phase B: combine + store
#pragma unroll
        for (int j = 0; j < GRP; ++j) {
            const int k   = g * GRP + j;
            const int row = blk + k * NBLK;
            f4 v = r[j];
            const f4 z = {0.f, 0.f, 0.f, 0.f};
            v += (src[k] >= 0) ? h[j] : z;             // cndmask, no branch
            __builtin_nontemporal_store(v, &out[(size_t)row * H4 + t]);
        }
    }
}

extern "C" void kernel_launch(void* const* d_in, const int* in_sizes, int n_in,
                              void* d_out, int out_size, void* d_ws, size_t ws_size,
                              hipStream_t stream) {
    const float* hidden   = (const float*)d_in[0];
    // d_in[1] = attention_mask (unused by reference)
    const int*   counts   = (const int*)d_in[2];
    const float* residual = (const float*)d_in[3];
    // d_in[4] = residual_attention_mask (unused by reference)
    float* out = (float*)d_out;

    int* inv = (int*)d_ws;               // B*RES_S ints = 128 KiB

    build_inv_kernel<<<BB, 1024, 0, stream>>>(counts, inv);
    fanout_add_kernel<<<NBLK, TPB, 0, stream>>>(
        (const f4*)hidden, (const f4*)residual, inv, (f4*)out);
}

// Round 5
// 54.107 us; speedup vs baseline: 1.1754x; 1.1754x over previous
//
#include <hip/hip_runtime.h>
#include <hip/hip_bf16.h>

#define BB     8
#define NEW_S  2048
#define RES_S  4096
#define H4     256            // float4 per 1024-float row
#define TPB    256
#define RPB    16             // rows per block
#define NBLK   (BB * RES_S / RPB)   // 2048 blocks = 8/CU
#define GRP    2              // rows per pipeline group

typedef float f4 __attribute__((ext_vector_type(4)));

// ---------------------------------------------------------------------------
// Fused kernel. Per block: (1) scan this batch's 2048 counts (8 KB, L2-hit
// across the 256 blocks of the batch) to build the 16-entry inverse map for
// its contiguous row range; (2) stream 16 rows with a forced depth-2
// load/consume pipeline (sched_barrier stops the backend from sinking loads).
// out[b,j,:] = residual[b,j,:] + (inv[j]>=0 ? hidden[b,inv[j],:] : 0)
// ---------------------------------------------------------------------------
__global__ __launch_bounds__(TPB, 8) void fanout_fused_kernel(
    const f4* __restrict__ hidden,
    const f4* __restrict__ residual,
    const int* __restrict__ counts,
    f4* __restrict__ out) {

    const int t   = threadIdx.x;          // 0..255
    const int blk = blockIdx.x;           // 0..2047
    const int bb  = blk >> 8;             // batch (256 blocks per batch)
    const int r0  = (blk & 255) * RPB;    // first local row in [0,4096)

    __shared__ int src_lds[RPB];
    __shared__ unsigned long long wsum[4];

    if (t < RPB) src_lds[t] = -1;

    // ---- block-local scan of counts[bb][0..2047], 8 tokens per thread ----
    const int4* cb4 = (const int4*)(counts + bb * NEW_S);
    const int4 ca = cb4[2 * t];
    const int4 cb = cb4[2 * t + 1];
    const int c[8] = {ca.x, ca.y, ca.z, ca.w, cb.x, cb.y, cb.z, cb.w};
    // pack: low32 = clamped count, high32 = nonpositive flag (break marker)
    unsigned long long e[8], p = 0;
#pragma unroll
    for (int j = 0; j < 8; ++j) {
        e[j] = (unsigned long long)(unsigned)(c[j] > 0 ? c[j] : 0) |
               ((unsigned long long)(c[j] <= 0) << 32);
        p += e[j];
    }
    const int lane = t & 63, wave = t >> 6;
    unsigned long long x = p;
#pragma unroll
    for (int d = 1; d < 64; d <<= 1) {
        unsigned long long y = __shfl_up(x, d, 64);
        if (lane >= d) x += y;
    }
    if (lane == 63) wsum[wave] = x;
    __syncthreads();
    if (t == 0) {
        unsigned long long acc = 0;
#pragma unroll
        for (int w = 0; w < 4; ++w) {
            const unsigned long long v = wsum[w];
            wsum[w] = acc; acc += v;
        }
    }
    __syncthreads();
    unsigned long long acc = wsum[wave] + (x - p);   // exclusive prefix
#pragma unroll
    for (int j = 0; j < 8; ++j) {
        acc += e[j];
        if ((acc >> 32) == 0ULL) {                   // no break in prefix
            const int l = (int)(acc & 0xffffffffULL) - 1 - r0;
            if (l >= 0 && l < RPB) src_lds[l] = 8 * t + j;   // unique writer
        }
    }
    __syncthreads();

    int srcv[RPB];
#pragma unroll
    for (int k = 0; k < RPB; ++k)
        srcv[k] = __builtin_amdgcn_readfirstlane(src_lds[k]);

    // ---- streaming: 16 contiguous rows, depth-2 forced pipeline ----
    const size_t rbase = ((size_t)bb * RES_S + r0) * H4 + t;  // residual/out
    const size_t hbase = ((size_t)bb * NEW_S) * H4 + t;       // hidden

    f4 rA[GRP], hA[GRP], rB[GRP], hB[GRP];

#define LOADG(g, rr, hh)                                                 \
    _Pragma("unroll")                                                    \
    for (int j = 0; j < GRP; ++j) {                                      \
        const int k = (g) * GRP + j;                                     \
        rr[j] = residual[rbase + (size_t)k * H4];                        \
        const int s = srcv[k] >= 0 ? srcv[k] : 0;  /* clamp: L2 hit */   \
        hh[j] = hidden[hbase + (size_t)s * H4];                          \
    }

#define CONSUME(g, rr, hh)                                               \
    _Pragma("unroll")                                                    \
    for (int j = 0; j < GRP; ++j) {                                      \
        const int k = (g) * GRP + j;                                     \
        f4 v = rr[j];                                                    \
        const f4 z = {0.f, 0.f, 0.f, 0.f};                               \
        v += (srcv[k] >= 0) ? hh[j] : z;           /* cndmask */         \
        __builtin_nontemporal_store(v, &out[rbase + (size_t)k * H4]);    \
    }

    LOADG(0, rA, hA);                       // prologue: fill pipe
    LOADG(1, rB, hB);
    __builtin_amdgcn_sched_barrier(0);
    CONSUME(0, rA, hA);
    LOADG(2, rA, hA);
    __builtin_amdgcn_sched_barrier(0);
    CONSUME(1, rB, hB);
    LOADG(3, rB, hB);
    __builtin_amdgcn_sched_barrier(0);
    CONSUME(2, rA, hA);
    LOADG(4, rA, hA);
    __builtin_amdgcn_sched_barrier(0);
    CONSUME(3, rB, hB);
    LOADG(5, rB, hB);
    __builtin_amdgcn_sched_barrier(0);
    CONSUME(4, rA, hA);
    LOADG(6, rA, hA);
    __builtin_amdgcn_sched_barrier(0);
    CONSUME(5, rB, hB);
    LOADG(7, rB, hB);
    __builtin_amdgcn_sched_barrier(0);
    CONSUME(6, rA, hA);
    CONSUME(7, rB, hB);                     // epilogue: drain

#undef LOADG
#undef CONSUME
}

extern "C" void kernel_launch(void* const* d_in, const int* in_sizes, int n_in,
                              void* d_out, int out_size, void* d_ws, size_t ws_size,
                              hipStream_t stream) {
    const float* hidden   = (const float*)d_in[0];
    // d_in[1] = attention_mask (unused by reference)
    const int*   counts   = (const int*)d_in[2];
    const float* residual = (const float*)d_in[3];
    // d_in[4] = residual_attention_mask (unused by reference)
    float* out = (float*)d_out;

    fanout_fused_kernel<<<NBLK, TPB, 0, stream>>>(
        (const f4*)hidden, (const f4*)residual, counts, (f4*)out);
}